// Round 9
// baseline (430.669 us; speedup 1.0000x reference)
//
#include <hip/hip_runtime.h>
#include <stdint.h>

typedef unsigned short u16;
typedef unsigned int u32;
typedef __attribute__((ext_vector_type(8))) short short8v;   // 8 bf16 = 4 VGPRs
typedef __attribute__((ext_vector_type(4))) float f32x4;

#define NB 16      // batches per block -> 512 blocks -> 2 blocks/CU
#define HISTN 64
#define TGEN 193   // L+1

// strides (elements)
#define S_NOISE 2048   // 256*8
#define S_HIST  192    // 64*3
#define S_GAP   386    // 193*2
#define S_OUT   771    // 257*3

#define HROW 104       // h row stride (u16): bank-uniform for b128 reads
#define L2E  1.442695041f
#define L2E2 2.885390082f

__device__ __forceinline__ float b2f(u16 u) { return __uint_as_float(((u32)u) << 16); }
__device__ __forceinline__ u16 f2b(float f) {
    u32 u = __float_as_uint(f);
    u32 r = (u + 0x7fffu + ((u >> 16) & 1u)) >> 16;
    return (u16)r;
}
__device__ __forceinline__ float rcp_(float x) { return __builtin_amdgcn_rcpf(x); }
__device__ __forceinline__ float ex2(float x) { return __builtin_amdgcn_exp2f(x); }
// pack 2 f32 -> 2 bf16 (RNE); lo = a, hi = b
__device__ __forceinline__ u32 cvtpk(float a, float b) {
    u32 r; asm("v_cvt_pk_bf16_f32 %0, %1, %2" : "=v"(r) : "v"(a), "v"(b)); return r;
}
// tanh from prescaled arg s = 2*log2e*x  (NaN-safe at saturation)
__device__ __forceinline__ float tanh2(float s) {
    return __builtin_fmaf(-2.0f, rcp_(1.0f + ex2(s)), 1.0f);
}
// LSTM gate epilogue on prescaled pre-acts: a0,a1,a3 = -log2e*pre(i,f,o), a2 = 2log2e*pre(g)
__device__ __forceinline__ float cellh(const f32x4 a, float& c) {
    float iv = rcp_(1.0f + ex2(a[0]));
    float fv = rcp_(1.0f + ex2(a[1]));
    float gv = tanh2(a[2]);
    float ov = rcp_(1.0f + ex2(a[3]));
    c = __builtin_fmaf(fv, c, iv * gv);
    return ov * tanh2(L2E2 * c);
}
__device__ __forceinline__ float ldv(const void* p, int idx, bool f32) {
    return f32 ? ((const float*)p)[idx] : b2f(((const u16*)p)[idx]);
}
// LDS-only barrier: drain LDS ops; global prefetch rides across (no vmcnt drain)
__device__ __forceinline__ void sync_lds() {
    asm volatile("s_waitcnt lgkmcnt(0)" ::: "memory");
    __builtin_amdgcn_s_barrier();
}

extern "C" __global__ void __launch_bounds__(512, 4)
lstm_gen_kernel(const void* __restrict__ noise, const void* __restrict__ hist_x,
                const void* __restrict__ gap, const void* __restrict__ pW_ih,
                const void* __restrict__ pW_hh, const void* __restrict__ pb_ih,
                const void* __restrict__ pb_hh, const void* __restrict__ pW1,
                const void* __restrict__ pb1, const void* __restrict__ pW2,
                const void* __restrict__ pb2, void* __restrict__ out)
{
    __shared__ u16 hb[2][NB * HROW];       // double-buffered h, 6656 B
    __shared__ u16 cxs[HISTN][NB][16];     // cond x-fragment rows, 32768 B
    __shared__ u16 xr[32][NB][16];         // gen x ring (gd|0|noise), 16384 B
    __shared__ float zpl[NB * 4];          // MLP per-wave partials, 256 B
    __shared__ float dpd[NB];              // dist handoff cond->gen, 64 B

    const int tid = threadIdx.x;
    const int lane = tid & 63;
    const int w = tid >> 6;        // wave 0..7; owns units {8w+2lg+T}
    const int lg = lane >> 4;      // k-group / C-row group
    const int ln = lane & 15;      // A-row / batch column

    // ---- dtype detection (proven logic) ----
    bool is_f32 = false;
    {
        const u32* p = (const u32*)pW_hh;
        for (int i = 0; i < 64; i++) {
            u32 v = p[i];
            float a = b2f((u16)(v & 0xffffu));
            float bb = b2f((u16)(v >> 16));
            if (!(fabsf(a) <= 0.5f) || !(fabsf(bb) <= 0.5f)) is_f32 = true;
        }
    }

    float* hs = (float*)xr;   // prestage scratch: hist fp32 (12288 B <= 16384 B)

    // ======== prestage P1a: zero h, hist fp32 scratch, cond noise, hist->out ====
    for (int i = tid; i < NB * HROW; i += 512) ((u32*)hb)[i] = 0u;   // both buffers
    for (int i = tid; i < HISTN * NB * 3; i += 512) {
        int t = i / 48, r = i % 48, b = r / 3, k = r % 3;
        hs[i] = ldv(hist_x, ((size_t)blockIdx.x * NB + b) * S_HIST + t * 3 + k, is_f32);
    }
    for (int i = tid; i < HISTN * NB * 4; i += 512) {
        int t = i >> 6, r = i & 63, b = r >> 2, q = r & 3;
        size_t base = ((size_t)blockIdx.x * NB + b) * S_NOISE + t * 8;
        u32 v;
        if (is_f32) {
            const float* p = (const float*)noise + base + q * 2;
            v = (u32)f2b(p[0]) | ((u32)f2b(p[1]) << 16);
        } else v = ((const u32*)noise)[(base >> 1) + q];
        ((u32*)&cxs[t][b][8])[q] = v;
    }
    for (int i = tid; i < NB * HISTN * 3; i += 512) {   // exact hist -> out copy
        int b = i / 192, e = i % 192;
        size_t bt = (size_t)blockIdx.x * NB + b;
        if (is_f32) ((float*)out)[bt * S_OUT + e] = ((const float*)hist_x)[bt * S_HIST + e];
        else ((u16*)out)[bt * S_OUT + e] = ((const u16*)hist_x)[bt * S_HIST + e];
    }
    __syncthreads();

    // ======== prestage P1b: per-batch cumsum + cond-x pack (16 lanes) ========
    if (tid < NB) {
        float dd = 0.0f;
#pragma unroll 1
        for (int t = 0; t < HISTN; t++) {
            float x0 = hs[t * 48 + tid * 3 + 0];
            float x1 = hs[t * 48 + tid * 3 + 1];
            float x2 = hs[t * 48 + tid * 3 + 2];
            dd += x2;
            u16 dph = f2b(x2); u16 dpl = f2b(x2 - b2f(dph));
            u16 dsh = f2b(dd); u16 dsl = f2b(dd - b2f(dsh));
            u32* dst = (u32*)&cxs[t][tid][0];
            dst[0] = (u32)f2b(x0) | ((u32)f2b(x1) << 16);
            dst[1] = (u32)dph | ((u32)dpl << 16);
            dst[2] = (u32)dsh | ((u32)dsl << 16);
            dst[3] = (u32)dsh | ((u32)dph << 16);
        }
        dpd[tid] = dd;
    }
    __syncthreads();

    // ======== prestage P1c: gen x ring init (slots 0..31) ========
    {
        const int s = tid >> 4, b = tid & 15;   // 32 slots x 16 batches
        u32* row = (u32*)&xr[s][b][0];
        size_t gbase = ((size_t)blockIdx.x * NB + b) * S_GAP + s * 2;
        u32 gv;
        if (is_f32) {
            const float* p = (const float*)gap + gbase;
            gv = (u32)f2b(p[0]) | ((u32)f2b(p[1]) << 16);
        } else gv = *(const u32*)((const u16*)gap + gbase);
        row[0] = gv; row[1] = 0u; row[2] = 0u; row[3] = 0u;
        size_t nbase = ((size_t)blockIdx.x * NB + b) * S_NOISE + (size_t)(HISTN + s) * 8;
        u32 r0, r1, r2, r3;
        if (is_f32) {
            const float* nf = (const float*)noise + nbase;
            float4 a = *(const float4*)nf, bq = *(const float4*)(nf + 4);
            r0 = (u32)f2b(a.x) | ((u32)f2b(a.y) << 16);
            r1 = (u32)f2b(a.z) | ((u32)f2b(a.w) << 16);
            r2 = (u32)f2b(bq.x) | ((u32)f2b(bq.y) << 16);
            r3 = (u32)f2b(bq.z) | ((u32)f2b(bq.w) << 16);
        } else {
            uint4 nv = *(const uint4*)((const u16*)noise + nbase);
            r0 = nv.x; r1 = nv.y; r2 = nv.z; r3 = nv.w;
        }
        row[4] = r0; row[5] = r1; row[6] = r2; row[7] = r3;
    }

    // ---- persistent A fragments, PRESCALED, adjacent-unit permutation:
    // tile (w,T) covers units u = 8w + 2*(row>>2) + T, gate = row&3 ----
    short8v a00, a01, a02, a10, a11, a12;
#pragma unroll
    for (int T = 0; T < 2; T++) {
        const int u = (w << 3) | ((ln >> 2) << 1) | T;
        const int g = ln & 3;
        const int row = (g << 6) | u;
        const float rs = (g == 2) ? L2E2 : -L2E;
        float wdp = ldv(pW_ih, row * 12 + 2, is_f32) * rs;
        u16 wdph = f2b(wdp); u16 wdpl = f2b(wdp - b2f(wdph));
        float wds = ldv(pW_ih, row * 12 + 3, is_f32) * rs;
        u16 wdsh = f2b(wds); u16 wdsl = f2b(wds - b2f(wdsh));
        short8v f0, f1, f2;
#pragma unroll
        for (int e = 0; e < 8; e++) {
            const int c = lg * 8 + e;
            f0[e] = (short)f2b(ldv(pW_hh, row * 64 + c, is_f32) * rs);
            f1[e] = (short)f2b(ldv(pW_hh, row * 64 + 32 + c, is_f32) * rs);
            u16 v = 0;
            if (c == 0 || c == 1) v = f2b(ldv(pW_ih, row * 12 + c, is_f32) * rs);
            else if (c == 2 || c == 3) v = wdph;
            else if (c == 4 || c == 5) v = wdsh;
            else if (c == 6) v = wdsl;
            else if (c == 7) v = wdpl;
            else if (c >= 8 && c < 16) v = f2b(ldv(pW_ih, row * 12 + (c - 4), is_f32) * rs);
            f2[e] = (short)v;
        }
        if (T == 0) { a00 = f0; a01 = f1; a02 = f2; }
        else        { a10 = f0; a11 = f1; a12 = f2; }
    }

    // C-side: prescaled bias + dp/dist weight columns; unit u = 8w+2lg+T
    f32x4 bias0, bias1, wd0, wd1, ws0, ws1;
#pragma unroll
    for (int T = 0; T < 2; T++) {
        const int u = (w << 3) | (lg << 1) | T;
        f32x4 bv, dv, sv;
#pragma unroll
        for (int q = 0; q < 4; q++) {
            const int row = (q << 6) | u;
            const float qs = (q == 2) ? L2E2 : -L2E;
            bv[q] = (ldv(pb_ih, row, is_f32) + ldv(pb_hh, row, is_f32)) * qs;
            dv[q] = ldv(pW_ih, row * 12 + 2, is_f32) * qs;
            sv[q] = ldv(pW_ih, row * 12 + 3, is_f32) * qs;
        }
        if (T == 0) { bias0 = bv; wd0 = dv; ws0 = sv; }
        else        { bias1 = bv; wd1 = dv; ws1 = sv; }
    }

    // ---- MLP head fragments (waves 4..7), prescaled by 2log2e ----
    const bool mlpw = (w >= 4);
    short8v w1F0 = {}, w1F1 = {};
    f32x4 b1v = {0.f, 0.f, 0.f, 0.f};
    float w2L[4] = {0.f, 0.f, 0.f, 0.f};
    if (mlpw) {
        const int wp = w - 4;
        const int row1 = (wp << 4) | ln;
#pragma unroll
        for (int e = 0; e < 8; e++) {
            w1F0[e] = (short)f2b(ldv(pW1, row1 * 64 + lg * 8 + e, is_f32) * L2E2);
            w1F1[e] = (short)f2b(ldv(pW1, row1 * 64 + 32 + lg * 8 + e, is_f32) * L2E2);
        }
        const int rq = (wp << 4) | (lg << 2);
#pragma unroll
        for (int q = 0; q < 4; q++) {
            b1v[q] = ldv(pb1, rq + q, is_f32) * L2E2;
            w2L[q] = ldv(pW2, rq + q, is_f32) * L2E2;
        }
    }
    const float b2vs = ldv(pb2, 0, is_f32) * L2E2;

    // per-lane batch pointers (batch = ln)
    const size_t gb = (size_t)blockIdx.x * NB + (size_t)ln;
    const float* gd_f = (const float*)gap + gb * S_GAP;
    u16* out_h = (u16*)out + gb * S_OUT;
    float* out_f = (float*)out + gb * S_OUT;

    float cst0 = 0.f, cst1 = 0.f;
    int pc = 0;
    const int hoff = (w << 3) | (lg << 1);   // adjacent unit pair base
    __syncthreads();   // all prestage + fragments ready

    // x-fragment rotation register: holds the CURRENT step's x-row
    short8v bx = {};
    if (lg < 2) bx = *(const short8v*)&cxs[0][ln][lg * 8];

    // ================= conditioning: 64 steps, ONE barrier each =================
#pragma unroll 1
    for (int t = 0; t < HISTN; t++) {
        const u16* hc = hb[pc];
        u16* hn = hb[pc ^ 1];
        short8v bf0 = *(const short8v*)&hc[ln * HROW + lg * 8];
        short8v bf1 = *(const short8v*)&hc[ln * HROW + 32 + lg * 8];
        f32x4 acc0 = bias0, acc1 = bias1;
        acc0 = __builtin_amdgcn_mfma_f32_16x16x32_bf16(a00, bf0, acc0, 0, 0, 0);
        acc0 = __builtin_amdgcn_mfma_f32_16x16x32_bf16(a01, bf1, acc0, 0, 0, 0);
        acc0 = __builtin_amdgcn_mfma_f32_16x16x32_bf16(a02, bx, acc0, 0, 0, 0);
        acc1 = __builtin_amdgcn_mfma_f32_16x16x32_bf16(a10, bf0, acc1, 0, 0, 0);
        acc1 = __builtin_amdgcn_mfma_f32_16x16x32_bf16(a11, bf1, acc1, 0, 0, 0);
        acc1 = __builtin_amdgcn_mfma_f32_16x16x32_bf16(a12, bx, acc1, 0, 0, 0);
        float h0 = cellh(acc0, cst0);
        float h1 = cellh(acc1, cst1);
        *(u32*)&hn[ln * HROW + hoff] = cvtpk(h0, h1);   // adjacent units: one b32
        // prefetch next x-row (rides into the pre-barrier drain; value used post-barrier)
        short8v bxn = {};
        if (lg < 2) {
            if (t + 1 < HISTN) bxn = *(const short8v*)&cxs[t + 1][ln][lg * 8];
            else               bxn = *(const short8v*)&xr[0][ln][lg * 8];   // first gen row
        }
        sync_lds();
        bx = bxn;
        pc ^= 1;
    }
    // pc == 0; final h in hb[0]; bx holds gen step 0's x-row

    float dist = dpd[ln];          // replicated per-batch dist after cumsum
    float gdf0 = 0.f, gdf1 = 0.f;  // writer fp32 gd prefetch (exact out path)
    if (is_f32 && tid < NB) { gdf0 = gd_f[0]; gdf1 = gd_f[1]; }

    // ================= generation: 193 steps, TWO barriers =================
#pragma unroll 1
    for (int tg = 0; tg < TGEN; tg++) {
        u16* hB = hb[0];
        short8v bf0 = *(const short8v*)&hB[ln * HROW + lg * 8];
        short8v bf1 = *(const short8v*)&hB[ln * HROW + 32 + lg * 8];
        f32x4 acc0 = bias0, acc1 = bias1;
        acc0 = __builtin_amdgcn_mfma_f32_16x16x32_bf16(a00, bf0, acc0, 0, 0, 0);
        acc0 = __builtin_amdgcn_mfma_f32_16x16x32_bf16(a01, bf1, acc0, 0, 0, 0);
        acc0 = __builtin_amdgcn_mfma_f32_16x16x32_bf16(a02, bx, acc0, 0, 0, 0);
        acc1 = __builtin_amdgcn_mfma_f32_16x16x32_bf16(a10, bf0, acc1, 0, 0, 0);
        acc1 = __builtin_amdgcn_mfma_f32_16x16x32_bf16(a11, bf1, acc1, 0, 0, 0);
        acc1 = __builtin_amdgcn_mfma_f32_16x16x32_bf16(a12, bx, acc1, 0, 0, 0);
        if (mlpw) {
            f32x4 m0 = b1v;
            m0 = __builtin_amdgcn_mfma_f32_16x16x32_bf16(w1F0, bf0, m0, 0, 0, 0);
            m0 = __builtin_amdgcn_mfma_f32_16x16x32_bf16(w1F1, bf1, m0, 0, 0, 0);
            float mp = w2L[0] * tanh2(m0[0]) + w2L[1] * tanh2(m0[1])
                     + w2L[2] * tanh2(m0[2]) + w2L[3] * tanh2(m0[3]);
            mp += __shfl_xor(mp, 16);
            mp += __shfl_xor(mp, 32);
            if (lg == 0) zpl[(ln << 2) | (w - 4)] = mp;
        }
        // ring refill (waves 0..3): once per 16 steps, slots tg+16..tg+31
        if (((tg & 15) == 0) && tg > 0 && tg <= 176 && tid < 256) {
            const int s = tid >> 4, b = tid & 15;
            const int tga = tg + 16 + s;            // target gen step
            u32* row = (u32*)&xr[tga & 31][b][0];
            u32 gv = 0;
            if (tga < TGEN) {
                size_t gbase = ((size_t)blockIdx.x * NB + b) * S_GAP + tga * 2;
                if (is_f32) {
                    const float* p = (const float*)gap + gbase;
                    gv = (u32)f2b(p[0]) | ((u32)f2b(p[1]) << 16);
                } else gv = *(const u32*)((const u16*)gap + gbase);
            }
            row[0] = gv;
            u32 r0 = 0, r1 = 0, r2 = 0, r3 = 0;
            if (HISTN + tga < 256) {
                size_t nbase = ((size_t)blockIdx.x * NB + b) * S_NOISE + (size_t)(HISTN + tga) * 8;
                if (is_f32) {
                    const float* nf = (const float*)noise + nbase;
                    float4 a = *(const float4*)nf, bq = *(const float4*)(nf + 4);
                    r0 = (u32)f2b(a.x) | ((u32)f2b(a.y) << 16);
                    r1 = (u32)f2b(a.z) | ((u32)f2b(a.w) << 16);
                    r2 = (u32)f2b(bq.x) | ((u32)f2b(bq.y) << 16);
                    r3 = (u32)f2b(bq.z) | ((u32)f2b(bq.w) << 16);
                } else {
                    uint4 nv = *(const uint4*)((const u16*)noise + nbase);
                    r0 = nv.x; r1 = nv.y; r2 = nv.z; r3 = nv.w;
                }
            }
            row[4] = r0; row[5] = r1; row[6] = r2; row[7] = r3;
        }
        sync_lds();   // B1: zpl visible, h reads complete
        // ---- P2: head finish (replicated) + dp/dist epilogue + gates ----
        f32x4 zr = *(const f32x4*)&zpl[ln << 2];
        // prefetch next step's x-row early: overlaps the trans-chain epilogue
        short8v bxn = {};
        if (lg < 2) bxn = *(const short8v*)&xr[(tg + 1) & 31][ln][lg * 8];
        float th = tanh2(b2vs + zr[0] + zr[1] + zr[2] + zr[3]);
        float dp = 24.0f * th;
        dist += dp;
#pragma unroll
        for (int q = 0; q < 4; q++) {
            acc0[q] = __builtin_fmaf(wd0[q], dp, __builtin_fmaf(ws0[q], dist, acc0[q]));
            acc1[q] = __builtin_fmaf(wd1[q], dp, __builtin_fmaf(ws1[q], dist, acc1[q]));
        }
        float h0 = cellh(acc0, cst0);
        float h1 = cellh(acc1, cst1);
        *(u32*)&hB[ln * HROW + hoff] = cvtpk(h0, h1);
        if (tid < NB) {
            const int to = HISTN + tg;
            if (is_f32) {
                out_f[to * 3] = gdf0; out_f[to * 3 + 1] = gdf1; out_f[to * 3 + 2] = dp;
                if (tg + 1 < TGEN) { gdf0 = gd_f[(tg + 1) * 2]; gdf1 = gd_f[(tg + 1) * 2 + 1]; }
            } else {
                // writer lanes are lg==0: bx[0..1] hold this step's gd already
                out_h[to * 3] = (u16)bx[0];
                out_h[to * 3 + 1] = (u16)bx[1];
                out_h[to * 3 + 2] = f2b(dp);
            }
        }
        sync_lds();   // B2: h_t visible
        bx = bxn;
    }
}

extern "C" void kernel_launch(void* const* d_in, const int* in_sizes, int n_in,
                              void* d_out, int out_size, void* d_ws, size_t ws_size,
                              hipStream_t stream) {
    (void)in_sizes; (void)n_in; (void)d_ws; (void)ws_size; (void)out_size;
    lstm_gen_kernel<<<512, 512, 0, stream>>>(
        d_in[0], d_in[1], d_in[2], d_in[3], d_in[4], d_in[5],
        d_in[6], d_in[7], d_in[8], d_in[9], d_in[10], d_out);
}